// Round 15
// baseline (396.110 us; speedup 1.0000x reference)
//
#include <hip/hip_runtime.h>

// ---------- helpers ----------
typedef __attribute__((ext_vector_type(8))) short short8;
typedef __attribute__((ext_vector_type(4))) float f32x4;

__device__ __forceinline__ unsigned short f2bf(float f) {
    union { float f; unsigned u; } v; v.f = f;
    unsigned r = v.u + 0x7FFFu + ((v.u >> 16) & 1u);   // RNE
    return (unsigned short)(r >> 16);
}
__device__ __forceinline__ float bf2f(unsigned short h) {
    union { unsigned u; float f; } v; v.u = ((unsigned)h) << 16;
    return v.f;
}

// fast tanh: 1 v_exp_f32 + 1 v_rcp_f32. rel err ~1e-5 << bf16 ulp.
__device__ __forceinline__ float tanh_fast(float x) {
    float xc = fminf(fmaxf(x, -9.0f), 9.0f);
    float t  = __expf(2.0f * xc);
    return (t - 1.0f) * __builtin_amdgcn_rcpf(t + 1.0f);
}

#define GLD16(gptr, lptr)                                                     \
    __builtin_amdgcn_global_load_lds(                                         \
        (const __attribute__((address_space(1))) unsigned int*)(gptr),        \
        (__attribute__((address_space(3))) unsigned int*)(lptr), 16, 0, 0)

// ---------- FAT: edge histogram (FIRST) + merged casts ----------
// Blocks [0, eblk): edge_hist — dependency-ready at dispatch (deg pre-zeroed),
// runs concurrently under the cast instead of as a serial tail.
// Blocks [eblk, ..): x|W1|W2|W3 f32->bf16.
__global__ __launch_bounds__(256) void cast_hist(
    const float* __restrict__ x,  unsigned short* __restrict__ xbf,
    const float* __restrict__ W1, unsigned short* __restrict__ w1bf,
    const float* __restrict__ W2, unsigned short* __restrict__ w2bf,
    const float* __restrict__ W3, unsigned short* __restrict__ w3bf,
    int xq, int eblk,
    const int* __restrict__ ei, const float* __restrict__ alpha,
    unsigned long long* __restrict__ deg, int E)
{
    if ((int)blockIdx.x < eblk) {                  // ---- edge_hist blocks ----
        int e = blockIdx.x * 256 + threadIdx.x;
        if (e < E) {
            int dst = ei[E + e];
            float gate = 2.0f * fmaxf(alpha[e] - 0.5f, 0.0f);
            atomicAdd(&deg[dst], 0x100000000ULL | (gate > 0.0f ? 1ULL : 0ULL));
        }
        return;
    }
    int t = (blockIdx.x - eblk) * 256 + threadIdx.x;
    const float* s; unsigned short* d; int q;
    if (t < xq) { s = x; d = xbf; q = t; }
    else {
        int u = t - xq;
        if (u < 32768)      { s = W1; d = w1bf; q = u; }
        else if (u < 65536) { s = W2; d = w2bf; q = u - 32768; }
        else if (u < 73728) { s = W3; d = w3bf; q = u - 65536; }
        else return;
    }
    int base = q * 4;
    float4 v = *(const float4*)(s + base);
    unsigned long long p =
        (unsigned long long)f2bf(v.x)
      | ((unsigned long long)f2bf(v.y) << 16)
      | ((unsigned long long)f2bf(v.z) << 32)
      | ((unsigned long long)f2bf(v.w) << 48);
    *(unsigned long long*)(d + base) = p;
}

#define TM 128
#define TN 128
#define BK 64

// ---------- FAT: CSR scan (FIRST) + GEMM1 (R0 body + XCD-sibling swizzle) ----------
// Blocks [0, nb1): per-1024-node exclusive scan with atomic global base
// (deg complete from previous dispatch -> runs immediately, hides under GEMM).
// Blocks [nb1, ..): gemm_bt.
__global__ __launch_bounds__(256) void gemm_bt_scan(
    const unsigned short* __restrict__ A, const unsigned short* __restrict__ B,
    const float* __restrict__ bias, unsigned short* __restrict__ C,
    int M, int N, int K,
    const unsigned long long* __restrict__ deg, int* __restrict__ rowptr,
    int* __restrict__ cursor, int* __restrict__ gcounter, int NN, int nb1)
{
    __shared__ __align__(16) short As[TM][BK];
    __shared__ __align__(16) short Bs[TM][BK];

    if ((int)blockIdx.x < nb1) {                   // ---- scan blocks ----
        int* sums = (int*)&As[0][0];
        int* base_sh = sums + 256;
        int base = blockIdx.x * 1024 + threadIdx.x * 4;
        int v[4];
        #pragma unroll
        for (int i = 0; i < 4; ++i) {
            int idx = base + i;
            v[i] = (idx < NN) ? (int)(deg[idx] & 0xffffffffULL) : 0;
        }
        int s = v[0] + v[1] + v[2] + v[3];
        sums[threadIdx.x] = s;
        __syncthreads();
        for (int off = 1; off < 256; off <<= 1) {
            int t = (threadIdx.x >= off) ? sums[threadIdx.x - off] : 0;
            __syncthreads();
            sums[threadIdx.x] += t;
            __syncthreads();
        }
        int excl = sums[threadIdx.x] - s;
        if (threadIdx.x == 255) *base_sh = atomicAdd(gcounter, sums[255]);
        __syncthreads();
        int run = *base_sh + excl;
        #pragma unroll
        for (int i = 0; i < 4; ++i) {
            int idx = base + i;
            if (idx < NN) { rowptr[idx] = run; cursor[idx] = run; }
            run += v[i];
        }
        return;
    }

    const int g  = blockIdx.x - nb1;
    const int bx = (g >> 5) * 8 + (g & 7);     // A-tile index (same XCD for all 4 sibs)
    const int by = (g >> 3) & 3;               // column block 0..3
    const int mblk = (M + TM - 1) / TM;
    if (bx >= mblk) return;

    const int tid  = threadIdx.x;
    const int wave = tid >> 6;
    const int lane = tid & 63;
    const int m0 = bx * TM;
    const int n0 = by * TN;
    const int wm = (wave >> 1) * 64;
    const int wn = (wave & 1) * 64;
    const int lm = lane & 15;
    const int quad = lane >> 4;

    const int srow = lane >> 3;
    const int scol = ((lane & 7) ^ srow) * 8;
    const int cc0 = (quad ^ (lm & 7)) * 8;
    const int cc1 = ((4 + quad) ^ (lm & 7)) * 8;

    f32x4 acc[4][4] = {};

    for (int k0 = 0; k0 < K; k0 += BK) {
        #pragma unroll
        for (int i = 0; i < 4; ++i) {
            int row = wave * 32 + i * 8;
            int gr = m0 + row + srow; if (gr >= M) gr = M - 1;
            GLD16(A + (size_t)gr * K + k0 + scol, &As[row][0]);
            GLD16(B + (size_t)(n0 + row + srow) * K + k0 + scol, &Bs[row][0]);
        }
        __syncthreads();

        #pragma unroll
        for (int ks = 0; ks < BK; ks += 32) {
            const int cc = (ks == 0) ? cc0 : cc1;
            short8 af[4], bf_[4];
            #pragma unroll
            for (int i = 0; i < 4; ++i) {
                af[i]  = *(const short8*)&As[wm + i * 16 + lm][cc];
                bf_[i] = *(const short8*)&Bs[wn + i * 16 + lm][cc];
            }
            #pragma unroll
            for (int im = 0; im < 4; ++im)
                #pragma unroll
                for (int in = 0; in < 4; ++in)
                    acc[im][in] = __builtin_amdgcn_mfma_f32_16x16x32_bf16(
                        af[im], bf_[in], acc[im][in], 0, 0, 0);
        }
        __syncthreads();
    }

    #pragma unroll
    for (int im = 0; im < 4; ++im) {
        int gm_base = m0 + wm + im * 16 + quad * 4;
        #pragma unroll
        for (int in = 0; in < 4; ++in) {
            int gn = n0 + wn + in * 16 + lm;
            float bv = bias[gn];
            #pragma unroll
            for (int r = 0; r < 4; ++r) {
                int gm = gm_base + r;
                if (gm < M) {
                    float v = tanh_fast(acc[im][in][r] + bv);
                    C[(size_t)gm * N + gn] = f2bf(v);
                }
            }
        }
    }
}

// ---------- FAT: edge_fill (FIRST) + fused GEMM2+GEMM3 (R10 layout) ----------
// Blocks [0, eblk): CSR fill (cursor ready from previous dispatch -> runs
// immediately, hides under the GEMM). Blocks [eblk, ..): gemm23.
__global__ __launch_bounds__(256) void gemm23_fill(
    const unsigned short* __restrict__ h1, const unsigned short* __restrict__ W2,
    const float* __restrict__ b2, const unsigned short* __restrict__ W3,
    const float* __restrict__ b3, unsigned short* __restrict__ hout, int M,
    const int* __restrict__ ei, const float* __restrict__ alpha,
    int* __restrict__ cursor, int2* __restrict__ recs, int E, int eblk)
{
    __shared__ __align__(16) short As[64][64];     // 8 KB  (h1 k-tiles)
    __shared__ __align__(16) short Bs[256][64];    // 32 KB (W2 k-tiles; reused for W3)
    __shared__ __align__(16) short h2s[64][264];   // 33 KB (+8 pad: 16B-aligned rows)

    if ((int)blockIdx.x < eblk) {                  // ---- edge_fill blocks ----
        int e = blockIdx.x * 256 + threadIdx.x;
        if (e < E) {
            float gate = 2.0f * fmaxf(alpha[e] - 0.5f, 0.0f);
            if (gate > 0.0f) {
                int dst = ei[E + e];
                int src = ei[e];
                int pos = atomicAdd(&cursor[dst], 1);
                recs[pos] = make_int2(src, __float_as_int(gate));
            }
        }
        return;
    }

    const int tid  = threadIdx.x;
    const int wave = tid >> 6;
    const int lane = tid & 63;
    const int m0 = (blockIdx.x - eblk) * 64;
    const int wm = (wave >> 1) * 32;
    const int lm = lane & 15;
    const int quad = lane >> 4;
    const int srow = lane >> 3;
    const int scol = ((lane & 7) ^ srow) * 8;
    const int cc0 = (quad ^ (lm & 7)) * 8;
    const int cc1 = ((4 + quad) ^ (lm & 7)) * 8;

    // ---- phase A: h2 = tanh(h1 @ W2^T + b2) ----
    {
        const int wn = (wave & 1) * 128;
        f32x4 acc[2][8] = {};
        for (int k0 = 0; k0 < 512; k0 += 64) {
            #pragma unroll
            for (int i = 0; i < 2; ++i) {             // A: 64 rows (16/wave)
                int r0 = wave * 16 + i * 8;
                int gr = m0 + r0 + srow; if (gr >= M) gr = M - 1;
                GLD16(h1 + (size_t)gr * 512 + k0 + scol, &As[r0][0]);
            }
            #pragma unroll
            for (int i = 0; i < 8; ++i) {             // W2: 256 rows (64/wave)
                int r0 = wave * 64 + i * 8;
                GLD16(W2 + (size_t)(r0 + srow) * 512 + k0 + scol, &Bs[r0][0]);
            }
            __syncthreads();
            #pragma unroll
            for (int ks = 0; ks < 64; ks += 32) {
                const int cc = (ks == 0) ? cc0 : cc1;
                short8 af[2], bf_[8];
                #pragma unroll
                for (int i = 0; i < 2; ++i) af[i]  = *(const short8*)&As[wm + i * 16 + lm][cc];
                #pragma unroll
                for (int i = 0; i < 8; ++i) bf_[i] = *(const short8*)&Bs[wn + i * 16 + lm][cc];
                #pragma unroll
                for (int im = 0; im < 2; ++im)
                    #pragma unroll
                    for (int in = 0; in < 8; ++in)
                        acc[im][in] = __builtin_amdgcn_mfma_f32_16x16x32_bf16(
                            af[im], bf_[in], acc[im][in], 0, 0, 0);
            }
            __syncthreads();
        }
        // epilogue -> LDS h2s
        #pragma unroll
        for (int im = 0; im < 2; ++im) {
            int rb = wm + im * 16 + quad * 4;
            #pragma unroll
            for (int in = 0; in < 8; ++in) {
                int col = wn + in * 16 + lm;
                float bv = b2[col];
                #pragma unroll
                for (int r = 0; r < 4; ++r)
                    h2s[rb + r][col] = (short)f2bf(tanh_fast(acc[im][in][r] + bv));
            }
        }
    }
    __syncthreads();

    // ---- phase B: h = h2s @ W3^T + b3 ----
    {
        const int wn = (wave & 1) * 64;
        short (*Bs3)[64] = (short(*)[64])&Bs[0][0];
        f32x4 acc[2][4] = {};
        for (int k0 = 0; k0 < 256; k0 += 64) {
            #pragma unroll
            for (int i = 0; i < 4; ++i) {             // W3: 128 rows (32/wave)
                int r0 = wave * 32 + i * 8;
                GLD16(W3 + (size_t)(r0 + srow) * 256 + k0 + scol, &Bs3[r0][0]);
            }
            __syncthreads();
            #pragma unroll
            for (int ks = 0; ks < 64; ks += 32) {
                const int cc = (ks == 0) ? cc0 : cc1;
                short8 af[2], bf_[4];
                #pragma unroll
                for (int i = 0; i < 2; ++i)
                    af[i] = *(const short8*)&h2s[wm + i * 16 + lm][k0 + ks + quad * 8];
                #pragma unroll
                for (int i = 0; i < 4; ++i)
                    bf_[i] = *(const short8*)&Bs3[wn + i * 16 + lm][cc];
                #pragma unroll
                for (int im = 0; im < 2; ++im)
                    #pragma unroll
                    for (int in = 0; in < 4; ++in)
                        acc[im][in] = __builtin_amdgcn_mfma_f32_16x16x32_bf16(
                            af[im], bf_[in], acc[im][in], 0, 0, 0);
            }
            __syncthreads();
        }
        #pragma unroll
        for (int im = 0; im < 2; ++im) {
            int gm_base = m0 + wm + im * 16 + quad * 4;
            #pragma unroll
            for (int in = 0; in < 4; ++in) {
                int gn = wn + in * 16 + lm;
                float bv = b3[gn];
                #pragma unroll
                for (int r = 0; r < 4; ++r) {
                    int gm = gm_base + r;
                    if (gm < M)
                        hout[(size_t)gm * 128 + gn] = f2bf(acc[im][in][r] + bv);
                }
            }
        }
    }
}

// ---------- per-node gather + mean: one wave/node, 4 edges/iter ----------
__global__ __launch_bounds__(256) void node_gather(
    const unsigned short* __restrict__ h, const unsigned long long* __restrict__ deg,
    const int* __restrict__ rowptr, const int2* __restrict__ recs,
    float* __restrict__ out, int N)
{
    int wave = threadIdx.x >> 6;
    int lane = threadIdx.x & 63;
    int node = blockIdx.x * 4 + wave;
    if (node >= N) return;
    unsigned long long d = deg[node];
    int dAll  = __builtin_amdgcn_readfirstlane((int)(d >> 32));
    int dG    = __builtin_amdgcn_readfirstlane((int)(d & 0xffffffffULL));
    int start = __builtin_amdgcn_readfirstlane(rowptr[node]);
    int qw = lane >> 4, ql = lane & 15;     // quarter-wave per edge; 16 lanes x 16B = row
    float a[8] = {};
    for (int j = 0; j < dG; j += 4) {
        int jj = j + qw;
        if (jj < dG) {                      // inactive quarter-waves issue no loads
            int2 rec = recs[start + jj];
            float gate = __int_as_float(rec.y);
            uint4 u = *(const uint4*)(h + ((size_t)rec.x << 7) + ql * 8);
            a[0] += bf2f((unsigned short)(u.x & 0xffffu)) * gate;
            a[1] += bf2f((unsigned short)(u.x >> 16)) * gate;
            a[2] += bf2f((unsigned short)(u.y & 0xffffu)) * gate;
            a[3] += bf2f((unsigned short)(u.y >> 16)) * gate;
            a[4] += bf2f((unsigned short)(u.z & 0xffffu)) * gate;
            a[5] += bf2f((unsigned short)(u.z >> 16)) * gate;
            a[6] += bf2f((unsigned short)(u.w & 0xffffu)) * gate;
            a[7] += bf2f((unsigned short)(u.w >> 16)) * gate;
        }
    }
    #pragma unroll
    for (int i = 0; i < 8; ++i) {
        a[i] += __shfl_xor(a[i], 16);
        a[i] += __shfl_xor(a[i], 32);
    }
    if (qw == 0) {
        float inv = 1.0f / fmaxf((float)dAll, 1.0f);
        float* op = out + ((size_t)node << 7) + ql * 8;
        *(float4*)(op)     = make_float4(a[0] * inv, a[1] * inv, a[2] * inv, a[3] * inv);
        *(float4*)(op + 4) = make_float4(a[4] * inv, a[5] * inv, a[6] * inv, a[7] * inv);
    }
}

// ---------- launch ----------
extern "C" void kernel_launch(void* const* d_in, const int* in_sizes, int n_in,
                              void* d_out, int out_size, void* d_ws, size_t ws_size,
                              hipStream_t stream) {
    const float* x     = (const float*)d_in[0];
    const float* alpha = (const float*)d_in[1];
    const int*   ei    = (const int*)d_in[2];
    const float* W1 = (const float*)d_in[4];
    const float* b1 = (const float*)d_in[5];
    const float* W2 = (const float*)d_in[6];
    const float* b2 = (const float*)d_in[7];
    const float* W3 = (const float*)d_in[8];
    const float* b3 = (const float*)d_in[9];
    float* out = (float*)d_out;

    const int N = in_sizes[0] / 256;   // 100000
    const int E = in_sizes[1];         // 640000
    const int IN = 256, H1 = 512, D = 128;

    char* ws = (char*)d_ws;
    size_t off = 0;
    auto take = [&](size_t bytes) { char* p = ws + off; off = (off + bytes + 255) & ~(size_t)255; return p; };
    unsigned short* xbf  = (unsigned short*)take((size_t)N * IN * 2);   // recs aliases this
    unsigned short* h1bf = (unsigned short*)take((size_t)N * H1 * 2);
    unsigned short* hbf  = (unsigned short*)take((size_t)N * D  * 2);
    unsigned short* w1bf = (unsigned short*)take((size_t)H1 * IN * 2);
    unsigned short* w2bf = (unsigned short*)take((size_t)256 * H1 * 2);
    unsigned short* w3bf = (unsigned short*)take((size_t)D * 256 * 2);
    // CSR metadata live from cast_hist onward -> small separate allocations
    unsigned long long* deg = (unsigned long long*)take((size_t)N * 8);
    int* gcounter = (int*)take(256);          // adjacent to deg: one memset covers both
    int* rowptr   = (int*)take((size_t)N * 4);
    int* cursor   = (int*)take((size_t)N * 4);
    // recs (5.12 MB) aliases xbf: written only in gemm23_fill (xbf dead), read in gather
    int2* recs = (int2*)xbf;

    dim3 blk(256);

    // ---- zero deg+gcounter first ----
    hipMemsetAsync(deg, 0, (size_t)N * 8 + 256, stream);

    // ---- hist (first) + cast (fat) ----
    const int xq = N * IN / 4;                      // 6.4M quads
    const int castB = (xq + 73728 + 255) / 256;     // 25288
    const int eblk  = (E + 255) / 256;              // 2500
    cast_hist<<<eblk + castB, blk, 0, stream>>>(
        x, xbf, W1, w1bf, W2, w2bf, W3, w3bf, xq, eblk, ei, alpha, deg, E);

    // ---- scan (first) + gemm_bt (fat) ----
    const int mblk = (N + TM - 1) / TM;             // 782
    const int g1 = ((mblk + 7) / 8) * 32;           // 3136 (98 groups of 32)
    const int nb1 = (N + 1023) / 1024;              // 98
    gemm_bt_scan<<<nb1 + g1, blk, 0, stream>>>(
        xbf, w1bf, b1, h1bf, N, H1, IN, deg, rowptr, cursor, gcounter, N, nb1);

    // ---- fill (first) + gemm23 (fat) ----
    const int gblk = (N + 63) / 64;                 // 1563
    gemm23_fill<<<eblk + gblk, blk, 0, stream>>>(
        h1bf, w2bf, b2, w3bf, b3, hbf, N, ei, alpha, cursor, recs, E, eblk);

    // ---- gather + mean ----
    node_gather<<<(N + 3) / 4, blk, 0, stream>>>(hbf, deg, rowptr, recs, out, N);
}

// Round 16
// 385.262 us; speedup vs baseline: 1.0282x; 1.0282x over previous
//
#include <hip/hip_runtime.h>

// ---------- helpers ----------
typedef __attribute__((ext_vector_type(8))) short short8;
typedef __attribute__((ext_vector_type(4))) float f32x4;

__device__ __forceinline__ unsigned short f2bf(float f) {
    union { float f; unsigned u; } v; v.f = f;
    unsigned r = v.u + 0x7FFFu + ((v.u >> 16) & 1u);   // RNE
    return (unsigned short)(r >> 16);
}
__device__ __forceinline__ float bf2f(unsigned short h) {
    union { unsigned u; float f; } v; v.u = ((unsigned)h) << 16;
    return v.f;
}

// fast tanh: 1 v_exp_f32 + 1 v_rcp_f32. rel err ~1e-5 << bf16 ulp.
__device__ __forceinline__ float tanh_fast(float x) {
    float xc = fminf(fmaxf(x, -9.0f), 9.0f);
    float t  = __expf(2.0f * xc);
    return (t - 1.0f) * __builtin_amdgcn_rcpf(t + 1.0f);
}

#define GLD16(gptr, lptr)                                                     \
    __builtin_amdgcn_global_load_lds(                                         \
        (const __attribute__((address_space(1))) unsigned int*)(gptr),        \
        (__attribute__((address_space(3))) unsigned int*)(lptr), 16, 0, 0)

// ---------- FAT: merged casts + edge histogram (helpers appended LAST —
// R14-proven; helpers-first regressed by delaying the main ramp) ----------
__global__ __launch_bounds__(256) void cast_hist(
    const float* __restrict__ x,  unsigned short* __restrict__ xbf,
    const float* __restrict__ W1, unsigned short* __restrict__ w1bf,
    const float* __restrict__ W2, unsigned short* __restrict__ w2bf,
    const float* __restrict__ W3, unsigned short* __restrict__ w3bf,
    int xq, int castB,
    const int* __restrict__ ei, const float* __restrict__ alpha,
    unsigned long long* __restrict__ deg, int E)
{
    if ((int)blockIdx.x >= castB) {                // ---- edge_hist blocks ----
        int e = (blockIdx.x - castB) * 256 + threadIdx.x;
        if (e < E) {
            int dst = ei[E + e];
            float gate = 2.0f * fmaxf(alpha[e] - 0.5f, 0.0f);
            atomicAdd(&deg[dst], 0x100000000ULL | (gate > 0.0f ? 1ULL : 0ULL));
        }
        return;
    }
    int t = blockIdx.x * 256 + threadIdx.x;
    const float* s; unsigned short* d; int q;
    if (t < xq) { s = x; d = xbf; q = t; }
    else {
        int u = t - xq;
        if (u < 32768)      { s = W1; d = w1bf; q = u; }
        else if (u < 65536) { s = W2; d = w2bf; q = u - 32768; }
        else if (u < 73728) { s = W3; d = w3bf; q = u - 65536; }
        else return;
    }
    int base = q * 4;
    float4 v = *(const float4*)(s + base);
    unsigned long long p =
        (unsigned long long)f2bf(v.x)
      | ((unsigned long long)f2bf(v.y) << 16)
      | ((unsigned long long)f2bf(v.z) << 32)
      | ((unsigned long long)f2bf(v.w) << 48);
    *(unsigned long long*)(d + base) = p;
}

#define TM 128
#define TN 128
#define BK 64

// ---------- FAT: GEMM1 (R0 body + R11 XCD-sibling swizzle) + CSR scan ----------
// Blocks [0, g1): gemm_bt. Blocks [g1, g1+nb1): per-1024-node exclusive scan
// with atomic global base (scan LDS reuses As).
__global__ __launch_bounds__(256) void gemm_bt_scan(
    const unsigned short* __restrict__ A, const unsigned short* __restrict__ B,
    const float* __restrict__ bias, unsigned short* __restrict__ C,
    int M, int N, int K,
    const unsigned long long* __restrict__ deg, int* __restrict__ rowptr,
    int* __restrict__ cursor, int* __restrict__ gcounter, int NN, int g1)
{
    __shared__ __align__(16) short As[TM][BK];
    __shared__ __align__(16) short Bs[TM][BK];

    if ((int)blockIdx.x >= g1) {                   // ---- scan blocks ----
        int* sums = (int*)&As[0][0];
        int* base_sh = sums + 256;
        int b = blockIdx.x - g1;
        int base = b * 1024 + threadIdx.x * 4;
        int v[4];
        #pragma unroll
        for (int i = 0; i < 4; ++i) {
            int idx = base + i;
            v[i] = (idx < NN) ? (int)(deg[idx] & 0xffffffffULL) : 0;
        }
        int s = v[0] + v[1] + v[2] + v[3];
        sums[threadIdx.x] = s;
        __syncthreads();
        for (int off = 1; off < 256; off <<= 1) {
            int t = (threadIdx.x >= off) ? sums[threadIdx.x - off] : 0;
            __syncthreads();
            sums[threadIdx.x] += t;
            __syncthreads();
        }
        int excl = sums[threadIdx.x] - s;
        if (threadIdx.x == 255) *base_sh = atomicAdd(gcounter, sums[255]);
        __syncthreads();
        int run = *base_sh + excl;
        #pragma unroll
        for (int i = 0; i < 4; ++i) {
            int idx = base + i;
            if (idx < NN) { rowptr[idx] = run; cursor[idx] = run; }
            run += v[i];
        }
        return;
    }

    const int g  = blockIdx.x;
    const int bx = (g >> 5) * 8 + (g & 7);     // A-tile index (same XCD for all 4 sibs)
    const int by = (g >> 3) & 3;               // column block 0..3
    const int mblk = (M + TM - 1) / TM;
    if (bx >= mblk) return;

    const int tid  = threadIdx.x;
    const int wave = tid >> 6;
    const int lane = tid & 63;
    const int m0 = bx * TM;
    const int n0 = by * TN;
    const int wm = (wave >> 1) * 64;
    const int wn = (wave & 1) * 64;
    const int lm = lane & 15;
    const int quad = lane >> 4;

    const int srow = lane >> 3;
    const int scol = ((lane & 7) ^ srow) * 8;
    const int cc0 = (quad ^ (lm & 7)) * 8;
    const int cc1 = ((4 + quad) ^ (lm & 7)) * 8;

    f32x4 acc[4][4] = {};

    for (int k0 = 0; k0 < K; k0 += BK) {
        #pragma unroll
        for (int i = 0; i < 4; ++i) {
            int row = wave * 32 + i * 8;
            int gr = m0 + row + srow; if (gr >= M) gr = M - 1;
            GLD16(A + (size_t)gr * K + k0 + scol, &As[row][0]);
            GLD16(B + (size_t)(n0 + row + srow) * K + k0 + scol, &Bs[row][0]);
        }
        __syncthreads();

        #pragma unroll
        for (int ks = 0; ks < BK; ks += 32) {
            const int cc = (ks == 0) ? cc0 : cc1;
            short8 af[4], bf_[4];
            #pragma unroll
            for (int i = 0; i < 4; ++i) {
                af[i]  = *(const short8*)&As[wm + i * 16 + lm][cc];
                bf_[i] = *(const short8*)&Bs[wn + i * 16 + lm][cc];
            }
            #pragma unroll
            for (int im = 0; im < 4; ++im)
                #pragma unroll
                for (int in = 0; in < 4; ++in)
                    acc[im][in] = __builtin_amdgcn_mfma_f32_16x16x32_bf16(
                        af[im], bf_[in], acc[im][in], 0, 0, 0);
        }
        __syncthreads();
    }

    #pragma unroll
    for (int im = 0; im < 4; ++im) {
        int gm_base = m0 + wm + im * 16 + quad * 4;
        #pragma unroll
        for (int in = 0; in < 4; ++in) {
            int gn = n0 + wn + in * 16 + lm;
            float bv = bias[gn];
            #pragma unroll
            for (int r = 0; r < 4; ++r) {
                int gm = gm_base + r;
                if (gm < M) {
                    float v = tanh_fast(acc[im][in][r] + bv);
                    C[(size_t)gm * N + gn] = f2bf(v);
                }
            }
        }
    }
}

// ---------- FAT: fused GEMM2+GEMM3 (R10 layout) + edge_fill ----------
// Blocks [0, gblk): gemm23. Blocks [gblk, ..): CSR fill (cursor ready from
// previous dispatch; fill drains during the GEMM's tail).
__global__ __launch_bounds__(256) void gemm23_fill(
    const unsigned short* __restrict__ h1, const unsigned short* __restrict__ W2,
    const float* __restrict__ b2, const unsigned short* __restrict__ W3,
    const float* __restrict__ b3, unsigned short* __restrict__ hout, int M,
    const int* __restrict__ ei, const float* __restrict__ alpha,
    int* __restrict__ cursor, int2* __restrict__ recs, int E, int gblk)
{
    __shared__ __align__(16) short As[64][64];     // 8 KB  (h1 k-tiles)
    __shared__ __align__(16) short Bs[256][64];    // 32 KB (W2 k-tiles; reused for W3)
    __shared__ __align__(16) short h2s[64][264];   // 33 KB (+8 pad: 16B-aligned rows)

    if ((int)blockIdx.x >= gblk) {                 // ---- edge_fill blocks ----
        int e = (blockIdx.x - gblk) * 256 + threadIdx.x;
        if (e < E) {
            float gate = 2.0f * fmaxf(alpha[e] - 0.5f, 0.0f);
            if (gate > 0.0f) {
                int dst = ei[E + e];
                int src = ei[e];
                int pos = atomicAdd(&cursor[dst], 1);
                recs[pos] = make_int2(src, __float_as_int(gate));
            }
        }
        return;
    }

    const int tid  = threadIdx.x;
    const int wave = tid >> 6;
    const int lane = tid & 63;
    const int m0 = blockIdx.x * 64;
    const int wm = (wave >> 1) * 32;
    const int lm = lane & 15;
    const int quad = lane >> 4;
    const int srow = lane >> 3;
    const int scol = ((lane & 7) ^ srow) * 8;
    const int cc0 = (quad ^ (lm & 7)) * 8;
    const int cc1 = ((4 + quad) ^ (lm & 7)) * 8;

    // ---- phase A: h2 = tanh(h1 @ W2^T + b2) ----
    {
        const int wn = (wave & 1) * 128;
        f32x4 acc[2][8] = {};
        for (int k0 = 0; k0 < 512; k0 += 64) {
            #pragma unroll
            for (int i = 0; i < 2; ++i) {             // A: 64 rows (16/wave)
                int r0 = wave * 16 + i * 8;
                int gr = m0 + r0 + srow; if (gr >= M) gr = M - 1;
                GLD16(h1 + (size_t)gr * 512 + k0 + scol, &As[r0][0]);
            }
            #pragma unroll
            for (int i = 0; i < 8; ++i) {             // W2: 256 rows (64/wave)
                int r0 = wave * 64 + i * 8;
                GLD16(W2 + (size_t)(r0 + srow) * 512 + k0 + scol, &Bs[r0][0]);
            }
            __syncthreads();
            #pragma unroll
            for (int ks = 0; ks < 64; ks += 32) {
                const int cc = (ks == 0) ? cc0 : cc1;
                short8 af[2], bf_[8];
                #pragma unroll
                for (int i = 0; i < 2; ++i) af[i]  = *(const short8*)&As[wm + i * 16 + lm][cc];
                #pragma unroll
                for (int i = 0; i < 8; ++i) bf_[i] = *(const short8*)&Bs[wn + i * 16 + lm][cc];
                #pragma unroll
                for (int im = 0; im < 2; ++im)
                    #pragma unroll
                    for (int in = 0; in < 8; ++in)
                        acc[im][in] = __builtin_amdgcn_mfma_f32_16x16x32_bf16(
                            af[im], bf_[in], acc[im][in], 0, 0, 0);
            }
            __syncthreads();
        }
        // epilogue -> LDS h2s
        #pragma unroll
        for (int im = 0; im < 2; ++im) {
            int rb = wm + im * 16 + quad * 4;
            #pragma unroll
            for (int in = 0; in < 8; ++in) {
                int col = wn + in * 16 + lm;
                float bv = b2[col];
                #pragma unroll
                for (int r = 0; r < 4; ++r)
                    h2s[rb + r][col] = (short)f2bf(tanh_fast(acc[im][in][r] + bv));
            }
        }
    }
    __syncthreads();

    // ---- phase B: h = h2s @ W3^T + b3 ----
    {
        const int wn = (wave & 1) * 64;
        short (*Bs3)[64] = (short(*)[64])&Bs[0][0];
        f32x4 acc[2][4] = {};
        for (int k0 = 0; k0 < 256; k0 += 64) {
            #pragma unroll
            for (int i = 0; i < 4; ++i) {             // W3: 128 rows (32/wave)
                int r0 = wave * 32 + i * 8;
                GLD16(W3 + (size_t)(r0 + srow) * 256 + k0 + scol, &Bs3[r0][0]);
            }
            __syncthreads();
            #pragma unroll
            for (int ks = 0; ks < 64; ks += 32) {
                const int cc = (ks == 0) ? cc0 : cc1;
                short8 af[2], bf_[4];
                #pragma unroll
                for (int i = 0; i < 2; ++i)
                    af[i] = *(const short8*)&h2s[wm + i * 16 + lm][k0 + ks + quad * 8];
                #pragma unroll
                for (int i = 0; i < 4; ++i)
                    bf_[i] = *(const short8*)&Bs3[wn + i * 16 + lm][cc];
                #pragma unroll
                for (int im = 0; im < 2; ++im)
                    #pragma unroll
                    for (int in = 0; in < 4; ++in)
                        acc[im][in] = __builtin_amdgcn_mfma_f32_16x16x32_bf16(
                            af[im], bf_[in], acc[im][in], 0, 0, 0);
            }
            __syncthreads();
        }
        #pragma unroll
        for (int im = 0; im < 2; ++im) {
            int gm_base = m0 + wm + im * 16 + quad * 4;
            #pragma unroll
            for (int in = 0; in < 4; ++in) {
                int gn = wn + in * 16 + lm;
                float bv = b3[gn];
                #pragma unroll
                for (int r = 0; r < 4; ++r) {
                    int gm = gm_base + r;
                    if (gm < M)
                        hout[(size_t)gm * 128 + gn] = f2bf(acc[im][in][r] + bv);
                }
            }
        }
    }
}

// ---------- per-node gather + mean: one wave/node, 4 edges/iter ----------
__global__ __launch_bounds__(256) void node_gather(
    const unsigned short* __restrict__ h, const unsigned long long* __restrict__ deg,
    const int* __restrict__ rowptr, const int2* __restrict__ recs,
    float* __restrict__ out, int N)
{
    int wave = threadIdx.x >> 6;
    int lane = threadIdx.x & 63;
    int node = blockIdx.x * 4 + wave;
    if (node >= N) return;
    unsigned long long d = deg[node];
    int dAll  = __builtin_amdgcn_readfirstlane((int)(d >> 32));
    int dG    = __builtin_amdgcn_readfirstlane((int)(d & 0xffffffffULL));
    int start = __builtin_amdgcn_readfirstlane(rowptr[node]);
    int qw = lane >> 4, ql = lane & 15;     // quarter-wave per edge; 16 lanes x 16B = row
    float a[8] = {};
    for (int j = 0; j < dG; j += 4) {
        int jj = j + qw;
        if (jj < dG) {                      // inactive quarter-waves issue no loads
            int2 rec = recs[start + jj];
            float gate = __int_as_float(rec.y);
            uint4 u = *(const uint4*)(h + ((size_t)rec.x << 7) + ql * 8);
            a[0] += bf2f((unsigned short)(u.x & 0xffffu)) * gate;
            a[1] += bf2f((unsigned short)(u.x >> 16)) * gate;
            a[2] += bf2f((unsigned short)(u.y & 0xffffu)) * gate;
            a[3] += bf2f((unsigned short)(u.y >> 16)) * gate;
            a[4] += bf2f((unsigned short)(u.z & 0xffffu)) * gate;
            a[5] += bf2f((unsigned short)(u.z >> 16)) * gate;
            a[6] += bf2f((unsigned short)(u.w & 0xffffu)) * gate;
            a[7] += bf2f((unsigned short)(u.w >> 16)) * gate;
        }
    }
    #pragma unroll
    for (int i = 0; i < 8; ++i) {
        a[i] += __shfl_xor(a[i], 16);
        a[i] += __shfl_xor(a[i], 32);
    }
    if (qw == 0) {
        float inv = 1.0f / fmaxf((float)dAll, 1.0f);
        float* op = out + ((size_t)node << 7) + ql * 8;
        *(float4*)(op)     = make_float4(a[0] * inv, a[1] * inv, a[2] * inv, a[3] * inv);
        *(float4*)(op + 4) = make_float4(a[4] * inv, a[5] * inv, a[6] * inv, a[7] * inv);
    }
}

// ---------- launch ----------
extern "C" void kernel_launch(void* const* d_in, const int* in_sizes, int n_in,
                              void* d_out, int out_size, void* d_ws, size_t ws_size,
                              hipStream_t stream) {
    const float* x     = (const float*)d_in[0];
    const float* alpha = (const float*)d_in[1];
    const int*   ei    = (const int*)d_in[2];
    const float* W1 = (const float*)d_in[4];
    const float* b1 = (const float*)d_in[5];
    const float* W2 = (const float*)d_in[6];
    const float* b2 = (const float*)d_in[7];
    const float* W3 = (const float*)d_in[8];
    const float* b3 = (const float*)d_in[9];
    float* out = (float*)d_out;

    const int N = in_sizes[0] / 256;   // 100000
    const int E = in_sizes[1];         // 640000
    const int IN = 256, H1 = 512, D = 128;

    char* ws = (char*)d_ws;
    size_t off = 0;
    auto take = [&](size_t bytes) { char* p = ws + off; off = (off + bytes + 255) & ~(size_t)255; return p; };
    unsigned short* xbf  = (unsigned short*)take((size_t)N * IN * 2);   // recs aliases this
    unsigned short* h1bf = (unsigned short*)take((size_t)N * H1 * 2);
    unsigned short* hbf  = (unsigned short*)take((size_t)N * D  * 2);
    unsigned short* w1bf = (unsigned short*)take((size_t)H1 * IN * 2);
    unsigned short* w2bf = (unsigned short*)take((size_t)256 * H1 * 2);
    unsigned short* w3bf = (unsigned short*)take((size_t)D * 256 * 2);
    // CSR metadata live from cast_hist onward -> small separate allocations
    unsigned long long* deg = (unsigned long long*)take((size_t)N * 8);
    int* gcounter = (int*)take(256);          // adjacent to deg: one memset covers both
    int* rowptr   = (int*)take((size_t)N * 4);
    int* cursor   = (int*)take((size_t)N * 4);
    // recs (5.12 MB) aliases xbf: written only in gemm23_fill (xbf dead), read in gather
    int2* recs = (int2*)xbf;

    dim3 blk(256);

    // ---- zero deg+gcounter first ----
    hipMemsetAsync(deg, 0, (size_t)N * 8 + 256, stream);

    // ---- cast + hist (fat) ----
    const int xq = N * IN / 4;                      // 6.4M quads
    const int castB = (xq + 73728 + 255) / 256;     // 25288
    const int eblk  = (E + 255) / 256;              // 2500
    cast_hist<<<castB + eblk, blk, 0, stream>>>(
        x, xbf, W1, w1bf, W2, w2bf, W3, w3bf, xq, castB, ei, alpha, deg, E);

    // ---- gemm_bt + scan (fat) ----
    const int mblk = (N + TM - 1) / TM;             // 782
    const int g1 = ((mblk + 7) / 8) * 32;           // 3136 (98 groups of 32)
    const int nb1 = (N + 1023) / 1024;              // 98
    gemm_bt_scan<<<g1 + nb1, blk, 0, stream>>>(
        xbf, w1bf, b1, h1bf, N, H1, IN, deg, rowptr, cursor, gcounter, N, g1);

    // ---- gemm23 + fill (fat) ----
    const int gblk = (N + 63) / 64;                 // 1563
    gemm23_fill<<<gblk + eblk, blk, 0, stream>>>(
        h1bf, w2bf, b2, w3bf, b3, hbf, N, ei, alpha, cursor, recs, E, gblk);

    // ---- gather + mean ----
    node_gather<<<(N + 3) / 4, blk, 0, stream>>>(hbf, deg, rowptr, recs, out, N);
}